// Round 4
// baseline (237.664 us; speedup 1.0000x reference)
//
#include <hip/hip_runtime.h>

// Zero timestep t (t & 3 == mask_idx) of x: [8, 8192, 512] fp32.
// Memory-bound: ideal traffic = 96 MiB read (skip masked quarter) + 128 MiB
// write -> ~36 us floor at 6.3 TB/s.
//
// Fast path: fixed geometry 2048 blocks x 256 threads, each thread does
// exactly 16 float4 at stride 524288. stride/128 = 4096 timesteps (mult of 4),
// so each thread's (t & 3) phase is LOOP-INVARIANT -> hoist the mask branch,
// fully unroll both paths (16 independent loads in flight).
// Nontemporal stores for `out` (never re-read) avoid evicting L3-warm `x`
// (the harness d2d-restores d_in right before each timed launch).
//
// NOTE: __builtin_nontemporal_store requires a clang-native vector type;
// HIP's float4 (HIP_vector_type class) is rejected -> use ext_vector_type.

#define PERIOD 4

typedef float f32x4 __attribute__((ext_vector_type(4)));

__global__ __launch_bounds__(256)
void pd_mask_fast(const f32x4* __restrict__ x,
                  const int* __restrict__ mask_p,
                  f32x4* __restrict__ out) {
    constexpr int STRIDE = 2048 * 256;           // total threads (in float4 units)
    constexpr int ITERS  = 16;
    const int tid = blockIdx.x * 256 + threadIdx.x;
    const int m = *mask_p;                        // uniform scalar load
    // t = float4_idx >> 7 (D=512 floats = 128 float4/timestep); phase is
    // invariant across the 16 iterations and uniform within a wave.
    if (((tid >> 7) & (PERIOD - 1)) == m) {
        const f32x4 zero = (f32x4){0.f, 0.f, 0.f, 0.f};
        #pragma unroll
        for (int k = 0; k < ITERS; ++k)
            __builtin_nontemporal_store(zero, &out[tid + k * STRIDE]);
    } else {
        #pragma unroll
        for (int k = 0; k < ITERS; ++k) {
            const f32x4 v = x[tid + k * STRIDE];     // cached: x may be L3-warm
            __builtin_nontemporal_store(v, &out[tid + k * STRIDE]);
        }
    }
}

// Generic fallback (any size), same structure as round-1 kernel.
__global__ __launch_bounds__(256)
void pd_mask_generic(const f32x4* __restrict__ x,
                     const int* __restrict__ mask_p,
                     f32x4* __restrict__ out, int n4) {
    const int m = *mask_p;
    const f32x4 zero = (f32x4){0.f, 0.f, 0.f, 0.f};
    const int stride = gridDim.x * blockDim.x;
    for (int i = blockIdx.x * blockDim.x + threadIdx.x; i < n4; i += stride) {
        const int t = i >> 7;
        if ((t & (PERIOD - 1)) == m)
            __builtin_nontemporal_store(zero, &out[i]);
        else
            __builtin_nontemporal_store(x[i], &out[i]);
    }
}

extern "C" void kernel_launch(void* const* d_in, const int* in_sizes, int n_in,
                              void* d_out, int out_size, void* d_ws, size_t ws_size,
                              hipStream_t stream) {
    const f32x4* x      = (const f32x4*)d_in[0];
    const int*   mask_p = (const int*)d_in[1];
    f32x4*       out    = (f32x4*)d_out;

    const int n4 = out_size / 4;                 // 8388608 float4
    constexpr int BLOCK = 256, GRID = 2048, ITERS = 16;

    if (n4 == GRID * BLOCK * ITERS) {
        pd_mask_fast<<<GRID, BLOCK, 0, stream>>>(x, mask_p, out);
    } else {
        int grid = (n4 + BLOCK - 1) / BLOCK;
        if (grid > 2048) grid = 2048;
        pd_mask_generic<<<grid, BLOCK, 0, stream>>>(x, mask_p, out, n4);
    }
}